// Round 13
// baseline (103.742 us; speedup 1.0000x reference)
//
#include <hip/hip_runtime.h>
#include <hip/hip_bf16.h>
#include <stdint.h>

// Galerkin self-attention, fused:
//   out = seq @ (wq.T @ blockdiag_h(kv[b,h]) @ wo.T) + bo
//   kv[b,h] = (1/S) * LN(k)_h^T @ LN(v)_h,   k = seq@wk.T, v = seq@wv.T
// v13: kv blocks process 128 tokens (2 sub-tiles of 64) accumulating the
//      outer product in registers -> P partials halve to 8.4MB (64/bh);
//      96KB LDS (x | kT | vT, vT no longer overwrites x -> fewer barriers);
//      grid 256 x 512thr (8 waves/CU, shown sufficient by r6==r12).
//      red loop 128->64. Other kernels = r12.
// ws layout (bytes):
//   0        wkf bf16 fragment-major [w8][kk][n][lane][8]
//   131072   wvf bf16 fragment-major
//   262144   wqT bf16 [256 i][256 j]        (written by gka_red blocks 0-15)
//   524288   kvf f32 [4 b][4 h][4096 frag]  (fragment order, by gka_red)
//   1310720  wcf bf16 fragment-major [b][o6][kk][n][lane][8]
// d_out doubles as scratch for P = bf16 partials [4 b][64 p][4 h][4096 frag]
// (8.4MB of the 33.5MB output buffer); gka_out fully overwrites d_out last.

#define EMBED 256
#define SEQ   8192
#define LN_EPS 1e-5f

using bf16x8 = __attribute__((ext_vector_type(8))) short;
using bf16x4 = __attribute__((ext_vector_type(4))) short;
using f32x4  = __attribute__((ext_vector_type(4))) float;

static __device__ __forceinline__ short f2bf(float f) {
  __hip_bfloat16 h = __float2bfloat16(f);
  return __builtin_bit_cast(short, h);
}
static __device__ __forceinline__ float bf2f(uint32_t u) {
  return __uint_as_float(u << 16);
}
static __device__ __forceinline__ bf16x8 cvt8(f32x4 a, f32x4 b) {
  bf16x8 v;
  v[0] = f2bf(a[0]); v[1] = f2bf(a[1]); v[2] = f2bf(a[2]); v[3] = f2bf(a[3]);
  v[4] = f2bf(b[0]); v[5] = f2bf(b[1]); v[6] = f2bf(b[2]); v[7] = f2bf(b[3]);
  return v;
}

#define MFMA16(a, b, c) __builtin_amdgcn_mfma_f32_16x16x32_bf16((a), (b), (c), 0, 0, 0)

// Stage 32 x 256 fp32 rows -> bf16 LDS (256 threads), rows 512B, byte^=(row&7)<<4
static __device__ __forceinline__ void stage_x32(char* smem, const float* __restrict__ src, int tid) {
#pragma unroll
  for (int i = 0; i < 4; ++i) {
    int g = tid + i * 256;              // 16B-granule index
    int row = g >> 5, c16 = g & 31;
    const f32x4* p = (const f32x4*)(src + row * EMBED + c16 * 8);
    *(bf16x8*)(smem + row * 512 + ((c16 * 16) ^ ((row & 7) << 4))) = cvt8(p[0], p[1]);
  }
}

// ---------------- prep: wk/wv -> fragment-major bf16 ----------------
__global__ void gka_prep(const float* __restrict__ wk, const float* __restrict__ wv,
                         unsigned short* __restrict__ wkf, unsigned short* __restrict__ wvf) {
  int blk = blockIdx.x, tid = threadIdx.x;
  int g = (blk & 31) * 256 + tid;         // [0, 8192) granule of 8 bf16
  const float* W = (blk < 32) ? wk : wv;
  unsigned short* D = (blk < 32) ? wkf : wvf;
  int w8 = g >> 11, kk = (g >> 8) & 7, n = (g >> 6) & 3, ln = g & 63;
  int row = w8 * 64 + n * 16 + (ln & 15);
  int c0 = kk * 32 + (ln >> 4) * 8;
  const f32x4* p = (const f32x4*)(W + row * 256 + c0);
  *(bf16x8*)(D + g * 8) = cvt8(p[0], p[1]);
}

// ---------------- pass A: 2 sub-tiles x (k/v GEMM + LN->LDS) + reg-accum kv ---------
// 8 waves: GEMM wave = (head h = wid&3, token-half mh = wid>>2), acc[2][4].
// LDS: [0,32K) x, [32K,64K) kT, [64K,96K) vT. Outer product wave = (h, e-half=mh).
__global__ __launch_bounds__(512, 4)
void gka_kv(const float* __restrict__ seq,
            const unsigned short* __restrict__ wkf, const unsigned short* __restrict__ wvf,
            const float* __restrict__ lkg, const float* __restrict__ lkb,
            const float* __restrict__ lvg, const float* __restrict__ lvb,
            unsigned short* __restrict__ P) {
  __shared__ char smem[98304];
  const int tid = threadIdx.x;
  const int lane = tid & 63;
  const int wid = tid >> 6;               // 0..7
  const int h = wid & 3, mh = wid >> 2;
  const int l15 = lane & 15, l4 = lane >> 4, l7 = lane & 7;
  const int tile = blockIdx.x;            // 256 blocks, 128 tokens each
  const int b = tile >> 6;
  const int ptile2 = tile & 63;

  f32x4 kvacc[4][2];                      // persists across sub-tiles
#pragma unroll
  for (int fd = 0; fd < 4; ++fd) { kvacc[fd][0] = (f32x4)0.0f; kvacc[fd][1] = (f32x4)0.0f; }

  for (int st = 0; st < 2; ++st) {        // two 64-token sub-tiles
    const int ptile = ptile2 * 2 + st;

    // stage x: 2048 granules / 512 threads
#pragma unroll
    for (int i = 0; i < 4; ++i) {
      int g = tid + i * 512;
      int row = g >> 5, c16 = g & 31;
      const f32x4* p = (const f32x4*)(seq + (size_t)(b * SEQ + ptile * 64 + row) * EMBED + c16 * 8);
      *(bf16x8*)(smem + row * 512 + ((c16 * 16) ^ ((row & 7) << 4))) = cvt8(p[0], p[1]);
    }
    __syncthreads();                      // x staged; also fences prev outer's kT/vT reads

#pragma unroll
    for (int mat = 0; mat < 2; ++mat) {   // 0: k -> kT @32K; 1: v -> vT @64K
      const unsigned short* Wf = mat ? wvf : wkf;
      const float* gp = mat ? lvg : lkg;
      const float* bp = mat ? lvb : lkb;
      float gv[4], bv[4];
#pragma unroll
      for (int n = 0; n < 4; ++n) { gv[n] = gp[n * 16 + l15]; bv[n] = bp[n * 16 + l15]; }

      f32x4 acc[2][4];
#pragma unroll
      for (int m = 0; m < 2; ++m)
#pragma unroll
        for (int n = 0; n < 4; ++n) acc[m][n] = (f32x4)0.0f;

#pragma unroll
      for (int kk = 0; kk < 8; ++kk) {    // K = 256, steps of 32
        bf16x8 af[2], bw[4];
#pragma unroll
        for (int m = 0; m < 2; ++m) {
          int row = mh * 32 + m * 16 + l15;
          af[m] = *(const bf16x8*)(smem + row * 512 + ((kk * 64 + l4 * 16) ^ (l7 << 4)));
        }
#pragma unroll
        for (int n = 0; n < 4; ++n) {     // fragment-major: 512B coalesced per wave
          size_t off = (((h * 8 + kk) * 4 + n) * 64 + lane) << 3;
          bw[n] = *(const bf16x8*)(Wf + off);
        }
#pragma unroll
        for (int m = 0; m < 2; ++m)
#pragma unroll
          for (int n = 0; n < 4; ++n)
            acc[m][n] = MFMA16(af[m], bw[n], acc[m][n]);
      }

      // LN over this wave's 32 token-rows x 64 head-cols; write transposed to LDS
      char* T = smem + 32768 + mat * 32768 + h * 8192;  // [64 d|e][64 s], 128B rows, swz
#pragma unroll
      for (int m = 0; m < 2; ++m) {
        float mu[4], rs[4];
#pragma unroll
        for (int r = 0; r < 4; ++r) {
          float s1 = 0.f, s2 = 0.f;
#pragma unroll
          for (int n = 0; n < 4; ++n) { float x = acc[m][n][r]; s1 += x; s2 += x * x; }
#pragma unroll
          for (int msk = 1; msk < 16; msk <<= 1) {
            s1 += __shfl_xor(s1, msk);
            s2 += __shfl_xor(s2, msk);
          }
          mu[r] = s1 * (1.f / 64.f);
          float var = s2 * (1.f / 64.f) - mu[r] * mu[r];
          rs[r] = rsqrtf(var + LN_EPS);
        }
#pragma unroll
        for (int n = 0; n < 4; ++n) {
          bf16x4 pk;
#pragma unroll
          for (int r = 0; r < 4; ++r)
            pk[r] = f2bf((acc[m][n][r] - mu[r]) * rs[r] * gv[n] + bv[n]);
          int d = n * 16 + l15;           // d&7 == l7
          int sb = mh * 64 + m * 32 + l4 * 8;   // byte of s0 = mh*32 + m*16 + l4*4
          *(bf16x4*)(T + d * 128 + (sb ^ (l7 << 4))) = pk;
        }
      }
    }

    __syncthreads();                      // kT + vT ready

    // outer product: wave = (head h, e-half eh=mh); ACCUMULATE into kvacc
    {
      const int eh = mh;
#pragma unroll
      for (int kk = 0; kk < 2; ++kk) {    // 64 tokens = 2 K-steps
        bf16x8 ak[4], b2[2];
#pragma unroll
        for (int fd = 0; fd < 4; ++fd) {
          int d = fd * 16 + l15;
          ak[fd] = *(const bf16x8*)(smem + 32768 + h * 8192 + d * 128 +
                                    ((kk * 64 + l4 * 16) ^ (l7 << 4)));
        }
#pragma unroll
        for (int c = 0; c < 2; ++c) {
          int e = (eh * 2 + c) * 16 + l15;
          b2[c] = *(const bf16x8*)(smem + 65536 + h * 8192 + e * 128 +
                                   ((kk * 64 + l4 * 16) ^ (l7 << 4)));
        }
#pragma unroll
        for (int fd = 0; fd < 4; ++fd)
#pragma unroll
          for (int c = 0; c < 2; ++c)
            kvacc[fd][c] = MFMA16(ak[fd], b2[c], kvacc[fd][c]);
      }
    }
    // next stage's post-stage __syncthreads orders stage(t+1)/LN(t+1) vs outer(t)
  }

  // store P in fragment order (flat layout as before): coalesced 512B
  unsigned short* Ph = P + ((size_t)((b * 64 + ptile2) * 4 + h) << 12);
#pragma unroll
  for (int fd = 0; fd < 4; ++fd)
#pragma unroll
    for (int c = 0; c < 2; ++c) {
      bf16x4 pk;
#pragma unroll
      for (int r = 0; r < 4; ++r) pk[r] = f2bf(kvacc[fd][c][r]);
      *(bf16x4*)(Ph + (fd * 4 + mh * 2 + c) * 256 + lane * 4) = pk;
    }
}

// ---------------- reduce: kvf = sum_p P (64 partials); blocks 0-15 build wqT ---------
__global__ __launch_bounds__(256)
void gka_red(const unsigned short* __restrict__ P, float* __restrict__ kvf,
             const float* __restrict__ wq, unsigned short* __restrict__ wqt) {
  __shared__ unsigned short T[64 * 66];
  int blk = blockIdx.x, tid = threadIdx.x;
  {
    int gtid = blk * 256 + tid;               // 131072 = 16384 quads x 8 chunks
    int chunk = gtid & 7;
    int qid = gtid >> 3;                      // (b<<12) | (h<<10) | t4
    int b = qid >> 12, h = (qid >> 10) & 3, t4 = qid & 1023;
    const unsigned short* p0 = P + ((size_t)(b * 256 + h) << 12) + t4 * 4;
    float s0 = 0.f, s1 = 0.f, s2 = 0.f, s3 = 0.f;
#pragma unroll
    for (int s = 0; s < 8; ++s) {             // 64 partials / 8 chunks
      int p = chunk * 8 + s;
      uint2 u = *(const uint2*)(p0 + ((size_t)p << 14));
      s0 += bf2f(u.x & 0xffffu); s1 += bf2f(u.x >> 16);
      s2 += bf2f(u.y & 0xffffu); s3 += bf2f(u.y >> 16);
    }
#pragma unroll
    for (int msk = 1; msk < 8; msk <<= 1) {
      s0 += __shfl_xor(s0, msk); s1 += __shfl_xor(s1, msk);
      s2 += __shfl_xor(s2, msk); s3 += __shfl_xor(s3, msk);
    }
    if (chunk == 0) {
      f32x4 r; r[0] = s0; r[1] = s1; r[2] = s2; r[3] = s3;
      *(f32x4*)(kvf + (qid << 2)) = r;
    }
  }

  if (blk < 16) {                         // 64x64 tile transpose wqt[i][j] = wq[j][i]
    int ti = blk >> 2, tj = blk & 3;
#pragma unroll
    for (int it = 0; it < 4; ++it) {
      int g = tid + it * 256;               // 1024 granules of 4 floats
      int jl = g >> 4, g4 = g & 15;
      f32x4 f = *(const f32x4*)(wq + (tj * 64 + jl) * 256 + ti * 64 + g4 * 4);
#pragma unroll
      for (int q = 0; q < 4; ++q) T[jl * 66 + g4 * 4 + q] = (unsigned short)f2bf(f[q]);
    }
    __syncthreads();
#pragma unroll
    for (int it = 0; it < 2; ++it) {
      int g = tid + it * 256;               // 512 output groups of 8
      int il = g >> 3, j8 = g & 7;
      bf16x8 v;
#pragma unroll
      for (int q = 0; q < 8; ++q) v[q] = (short)T[(j8 * 8 + q) * 66 + il];
      *(bf16x8*)(wqt + (ti * 64 + il) * 256 + tj * 64 + j8 * 8) = v;
    }
  }
}

// ---------------- pass B (merged m1+wc): per (b, o-half) block ----------------------
// phase 1: M1T[o_loc][j=h*64+d] = sum_e kv[b,h,d,e]/S * wo[o][h*64+e]  -> LDS (swz)
// phase 2: WcT frag-major: Wc[i][o] = sum_j wqT[i][j] * M1T[o_loc][j]
__global__ __launch_bounds__(512)
void gka_wc(const float* __restrict__ kvf, const float* __restrict__ wo,
            const unsigned short* __restrict__ wqt, unsigned short* __restrict__ wcf) {
  __shared__ char M1[65536];              // [128 o_loc][256 j] bf16, 512B rows, swz
  const int tid = threadIdx.x;
  const int lane = tid & 63;
  const int wid = tid >> 6;               // 8 waves
  const int l15 = lane & 15, l4 = lane >> 4;
  const int blk = blockIdx.x;             // 8 = 4b x 2 o-half
  const int b = blk >> 1, oh = blk & 1;
  const float invS = 1.f / (float)SEQ;

  // ---- phase 1: wave -> (wo_t = wid>>2 o-64-range, wj = wid&3 head) ----
  {
    const int wo_t = wid >> 2, wj = wid & 3;
    const float* kvh = kvf + ((b * 4 + wj) << 12);
    f32x4 acc[4][4];
#pragma unroll
    for (int m = 0; m < 4; ++m)
#pragma unroll
      for (int n = 0; n < 4; ++n) acc[m][n] = (f32x4)0.0f;

#pragma unroll
    for (int kk = 0; kk < 2; ++kk) {      // K = 64 (e)
      bf16x8 af[4], bw[4];
#pragma unroll
      for (int m = 0; m < 4; ++m) {
        // gather (d = m*16+l15, e = kk*32+l4*8+j) from kv fragment layout
        int base = (m * 4 + kk * 2 + (l4 >> 1)) * 256 +
                   ((l15 >> 2) * 16 + (l4 & 1) * 8) * 4 + (l15 & 3);
        bf16x8 v;
#pragma unroll
        for (int j = 0; j < 8; ++j) v[j] = f2bf(kvh[base + j * 4] * invS);
        af[m] = v;
      }
#pragma unroll
      for (int n = 0; n < 4; ++n) {
        int o = oh * 128 + wo_t * 64 + n * 16 + l15;
        const f32x4* wp = (const f32x4*)(wo + (size_t)o * 256 + wj * 64 + kk * 32 + l4 * 8);
        bw[n] = cvt8(wp[0], wp[1]);
      }
#pragma unroll
      for (int m = 0; m < 4; ++m)
#pragma unroll
        for (int n = 0; n < 4; ++n)
          acc[m][n] = MFMA16(af[m], bw[n], acc[m][n]);
    }
    // store to LDS M1T: row = o_loc, col j = wj*64 + m*16 + l4*4 + r (bf16x4), swz
#pragma unroll
    for (int m = 0; m < 4; ++m)
#pragma unroll
      for (int n = 0; n < 4; ++n) {
        int row = wo_t * 64 + n * 16 + l15;
        int jb = (wj * 64 + m * 16 + l4 * 4) * 2;
        bf16x4 pk;
#pragma unroll
        for (int r = 0; r < 4; ++r) pk[r] = f2bf(acc[m][n][r]);
        *(bf16x4*)(M1 + row * 512 + (jb ^ ((row & 7) << 4))) = pk;
      }
  }

  __syncthreads();

  // ---- phase 2: wave -> (wi = wid>>1 i-64-range, wo2 = wid&1 o-64-range) ----
  {
    const int wi = wid >> 1, wo2 = wid & 1;
    f32x4 acc[4][4];
#pragma unroll
    for (int m = 0; m < 4; ++m)
#pragma unroll
      for (int n = 0; n < 4; ++n) acc[m][n] = (f32x4)0.0f;

#pragma unroll
    for (int kk = 0; kk < 8; ++kk) {      // K = 256 (j)
      bf16x8 af[4], bw[4];
#pragma unroll
      for (int m = 0; m < 4; ++m) {
        int i = wi * 64 + m * 16 + l15;
        af[m] = *(const bf16x8*)(wqt + i * 256 + kk * 32 + l4 * 8);
      }
#pragma unroll
      for (int n = 0; n < 4; ++n) {
        int row = wo2 * 64 + n * 16 + l15;
        bw[n] = *(const bf16x8*)(M1 + row * 512 +
                                 ((kk * 64 + l4 * 16) ^ ((row & 7) << 4)));
      }
#pragma unroll
      for (int m = 0; m < 4; ++m)
#pragma unroll
        for (int n = 0; n < 4; ++n)
          acc[m][n] = MFMA16(af[m], bw[n], acc[m][n]);
    }
    // store to fragment-major wcf for gka_out
    const int o6 = oh * 2 + wo2;
#pragma unroll
    for (int m = 0; m < 4; ++m)
#pragma unroll
      for (int n = 0; n < 4; ++n) {
        int kko = wi * 2 + (m >> 1);
        int laneo = ((m & 1) * 2 + (l4 >> 1)) * 16 + l15;
        int jo = (l4 & 1) * 4;
        bf16x4 pk;
#pragma unroll
        for (int r = 0; r < 4; ++r) pk[r] = f2bf(acc[m][n][r]);
        *(bf16x4*)(wcf + ((size_t)b << 16) +
                   (((((o6 * 8 + kko) * 4 + n) * 64) + laneo) << 3) + jo) = pk;
      }
  }
}

// ---------------- pass C: out = seq @ Wc[b] + bo  (1024 x 32-token tiles, LDS) -------
__global__ __launch_bounds__(256, 4)
void gka_out(const float* __restrict__ seq, const unsigned short* __restrict__ wcf,
             const float* __restrict__ bo, float* __restrict__ out) {
  __shared__ char smem[16384];
  const int tid = threadIdx.x;
  const int lane = tid & 63;
  const int wid = tid >> 6;               // wave -> o-range (64 cols)
  const int l15 = lane & 15, l4 = lane >> 4, l7 = lane & 7;
  const int tile = blockIdx.x;            // 1024 = 4b x 256 tiles of 32 rows
  const int b = tile >> 8;
  const int srow = (tile & 255) * 32;

  stage_x32(smem, seq + (size_t)(b * SEQ + srow) * EMBED, tid);

  const unsigned short* Wf = wcf + ((size_t)b << 16);
  float bov[4];
#pragma unroll
  for (int n = 0; n < 4; ++n) bov[n] = bo[wid * 64 + n * 16 + l15];

  f32x4 acc[2][4];
#pragma unroll
  for (int m = 0; m < 2; ++m)
#pragma unroll
    for (int n = 0; n < 4; ++n) acc[m][n] = (f32x4)0.0f;

  __syncthreads();

#pragma unroll
  for (int kk = 0; kk < 8; ++kk) {        // K = 256, no barriers
    bf16x8 af[2], bw[4];
#pragma unroll
    for (int m = 0; m < 2; ++m) {
      int row = m * 16 + l15;
      af[m] = *(const bf16x8*)(smem + row * 512 + ((kk * 64 + l4 * 16) ^ (l7 << 4)));
    }
#pragma unroll
    for (int n = 0; n < 4; ++n)           // coalesced 512B per wave, L2-resident
      bw[n] = *(const bf16x8*)(Wf + ((((wid * 8 + kk) * 4 + n) * 64 + lane) << 3));
#pragma unroll
    for (int m = 0; m < 2; ++m)
#pragma unroll
      for (int n = 0; n < 4; ++n)
        acc[m][n] = MFMA16(af[m], bw[n], acc[m][n]);
  }

  float* dst = out + (size_t)(b * SEQ + srow) * EMBED;
#pragma unroll
  for (int m = 0; m < 2; ++m)
#pragma unroll
    for (int n = 0; n < 4; ++n)
#pragma unroll
      for (int r = 0; r < 4; ++r)
        dst[(size_t)(m * 16 + l4 * 4 + r) * EMBED + wid * 64 + n * 16 + l15] =
            acc[m][n][r] + bov[n];
}

extern "C" void kernel_launch(void* const* d_in, const int* in_sizes, int n_in,
                              void* d_out, int out_size, void* d_ws, size_t ws_size,
                              hipStream_t stream) {
  const float* seq = (const float*)d_in[0];
  const float* wq  = (const float*)d_in[1];
  const float* wk  = (const float*)d_in[2];
  const float* wv  = (const float*)d_in[3];
  const float* wo  = (const float*)d_in[4];
  const float* bo  = (const float*)d_in[5];
  const float* lkg = (const float*)d_in[6];
  const float* lkb = (const float*)d_in[7];
  const float* lvg = (const float*)d_in[8];
  const float* lvb = (const float*)d_in[9];
  float* out = (float*)d_out;
  char* ws = (char*)d_ws;

  unsigned short* wkf = (unsigned short*)(ws + 0);
  unsigned short* wvf = (unsigned short*)(ws + 131072);
  unsigned short* wqt = (unsigned short*)(ws + 262144);
  float*          kvf = (float*)(ws + 524288);
  unsigned short* wcf = (unsigned short*)(ws + 1310720);
  unsigned short* P   = (unsigned short*)d_out;   // 8.4MB partials, overwritten by gka_out

  gka_prep<<<64, 256, 0, stream>>>(wk, wv, wkf, wvf);
  gka_kv<<<256, 512, 0, stream>>>(seq, wkf, wvf, lkg, lkb, lvg, lvb, P);
  gka_red<<<512, 256, 0, stream>>>(P, kvf, wq, wqt);
  gka_wc<<<8, 512, 0, stream>>>(kvf, wo, wqt, wcf);
  gka_out<<<1024, 256, 0, stream>>>(seq, wcf, bo, out);
}

// Round 14
// 101.262 us; speedup vs baseline: 1.0245x; 1.0245x over previous
//
#include <hip/hip_runtime.h>
#include <hip/hip_bf16.h>
#include <stdint.h>

// Galerkin self-attention, fused:
//   out = seq @ (wq.T @ blockdiag_h(kv[b,h]) @ wo.T) + bo
//   kv[b,h] = (1/S) * LN(k)_h^T @ LN(v)_h,   k = seq@wk.T, v = seq@wv.T
// v14: r13 with ONE change: gka_kv __launch_bounds__(512,4) -> (512,2).
//      r13's VGPR cap of 128 spilled the persistent kvacc working set
//      (VGPR_Count=128, WRITE 92.7MB vs 8.4MB expected). Cap 256 removes the
//      spill; occupancy 8 waves/CU = r6's proven-sufficient level. Keeps the
//      128-token amortization: P partials 8.4MB, weight L2 re-reads halved.
// ws layout (bytes):
//   0        wkf bf16 fragment-major [w8][kk][n][lane][8]
//   131072   wvf bf16 fragment-major
//   262144   wqT bf16 [256 i][256 j]        (written by gka_red blocks 0-15)
//   524288   kvf f32 [4 b][4 h][4096 frag]  (fragment order, by gka_red)
//   1310720  wcf bf16 fragment-major [b][o6][kk][n][lane][8]
// d_out doubles as scratch for P = bf16 partials [4 b][64 p][4 h][4096 frag]
// (8.4MB of the 33.5MB output buffer); gka_out fully overwrites d_out last.

#define EMBED 256
#define SEQ   8192
#define LN_EPS 1e-5f

using bf16x8 = __attribute__((ext_vector_type(8))) short;
using bf16x4 = __attribute__((ext_vector_type(4))) short;
using f32x4  = __attribute__((ext_vector_type(4))) float;

static __device__ __forceinline__ short f2bf(float f) {
  __hip_bfloat16 h = __float2bfloat16(f);
  return __builtin_bit_cast(short, h);
}
static __device__ __forceinline__ float bf2f(uint32_t u) {
  return __uint_as_float(u << 16);
}
static __device__ __forceinline__ bf16x8 cvt8(f32x4 a, f32x4 b) {
  bf16x8 v;
  v[0] = f2bf(a[0]); v[1] = f2bf(a[1]); v[2] = f2bf(a[2]); v[3] = f2bf(a[3]);
  v[4] = f2bf(b[0]); v[5] = f2bf(b[1]); v[6] = f2bf(b[2]); v[7] = f2bf(b[3]);
  return v;
}

#define MFMA16(a, b, c) __builtin_amdgcn_mfma_f32_16x16x32_bf16((a), (b), (c), 0, 0, 0)

// Stage 32 x 256 fp32 rows -> bf16 LDS (256 threads), rows 512B, byte^=(row&7)<<4
static __device__ __forceinline__ void stage_x32(char* smem, const float* __restrict__ src, int tid) {
#pragma unroll
  for (int i = 0; i < 4; ++i) {
    int g = tid + i * 256;              // 16B-granule index
    int row = g >> 5, c16 = g & 31;
    const f32x4* p = (const f32x4*)(src + row * EMBED + c16 * 8);
    *(bf16x8*)(smem + row * 512 + ((c16 * 16) ^ ((row & 7) << 4))) = cvt8(p[0], p[1]);
  }
}

// ---------------- prep: wk/wv -> fragment-major bf16 ----------------
__global__ void gka_prep(const float* __restrict__ wk, const float* __restrict__ wv,
                         unsigned short* __restrict__ wkf, unsigned short* __restrict__ wvf) {
  int blk = blockIdx.x, tid = threadIdx.x;
  int g = (blk & 31) * 256 + tid;         // [0, 8192) granule of 8 bf16
  const float* W = (blk < 32) ? wk : wv;
  unsigned short* D = (blk < 32) ? wkf : wvf;
  int w8 = g >> 11, kk = (g >> 8) & 7, n = (g >> 6) & 3, ln = g & 63;
  int row = w8 * 64 + n * 16 + (ln & 15);
  int c0 = kk * 32 + (ln >> 4) * 8;
  const f32x4* p = (const f32x4*)(W + row * 256 + c0);
  *(bf16x8*)(D + g * 8) = cvt8(p[0], p[1]);
}

// ---------------- pass A: 2 sub-tiles x (k/v GEMM + LN->LDS) + reg-accum kv ---------
// 8 waves: GEMM wave = (head h = wid&3, token-half mh = wid>>2), acc[2][4].
// LDS: [0,32K) x, [32K,64K) kT, [64K,96K) vT. Outer product wave = (h, e-half=mh).
__global__ __launch_bounds__(512, 2)
void gka_kv(const float* __restrict__ seq,
            const unsigned short* __restrict__ wkf, const unsigned short* __restrict__ wvf,
            const float* __restrict__ lkg, const float* __restrict__ lkb,
            const float* __restrict__ lvg, const float* __restrict__ lvb,
            unsigned short* __restrict__ P) {
  __shared__ char smem[98304];
  const int tid = threadIdx.x;
  const int lane = tid & 63;
  const int wid = tid >> 6;               // 0..7
  const int h = wid & 3, mh = wid >> 2;
  const int l15 = lane & 15, l4 = lane >> 4, l7 = lane & 7;
  const int tile = blockIdx.x;            // 256 blocks, 128 tokens each
  const int b = tile >> 6;
  const int ptile2 = tile & 63;

  f32x4 kvacc[4][2];                      // persists across sub-tiles
#pragma unroll
  for (int fd = 0; fd < 4; ++fd) { kvacc[fd][0] = (f32x4)0.0f; kvacc[fd][1] = (f32x4)0.0f; }

  for (int st = 0; st < 2; ++st) {        // two 64-token sub-tiles
    const int ptile = ptile2 * 2 + st;

    // stage x: 2048 granules / 512 threads
#pragma unroll
    for (int i = 0; i < 4; ++i) {
      int g = tid + i * 512;
      int row = g >> 5, c16 = g & 31;
      const f32x4* p = (const f32x4*)(seq + (size_t)(b * SEQ + ptile * 64 + row) * EMBED + c16 * 8);
      *(bf16x8*)(smem + row * 512 + ((c16 * 16) ^ ((row & 7) << 4))) = cvt8(p[0], p[1]);
    }
    __syncthreads();                      // x staged; also fences prev outer's kT/vT reads

#pragma unroll
    for (int mat = 0; mat < 2; ++mat) {   // 0: k -> kT @32K; 1: v -> vT @64K
      const unsigned short* Wf = mat ? wvf : wkf;
      const float* gp = mat ? lvg : lkg;
      const float* bp = mat ? lvb : lkb;
      float gv[4], bv[4];
#pragma unroll
      for (int n = 0; n < 4; ++n) { gv[n] = gp[n * 16 + l15]; bv[n] = bp[n * 16 + l15]; }

      f32x4 acc[2][4];
#pragma unroll
      for (int m = 0; m < 2; ++m)
#pragma unroll
        for (int n = 0; n < 4; ++n) acc[m][n] = (f32x4)0.0f;

#pragma unroll
      for (int kk = 0; kk < 8; ++kk) {    // K = 256, steps of 32
        bf16x8 af[2], bw[4];
#pragma unroll
        for (int m = 0; m < 2; ++m) {
          int row = mh * 32 + m * 16 + l15;
          af[m] = *(const bf16x8*)(smem + row * 512 + ((kk * 64 + l4 * 16) ^ (l7 << 4)));
        }
#pragma unroll
        for (int n = 0; n < 4; ++n) {     // fragment-major: 512B coalesced per wave
          size_t off = (((h * 8 + kk) * 4 + n) * 64 + lane) << 3;
          bw[n] = *(const bf16x8*)(Wf + off);
        }
#pragma unroll
        for (int m = 0; m < 2; ++m)
#pragma unroll
          for (int n = 0; n < 4; ++n)
            acc[m][n] = MFMA16(af[m], bw[n], acc[m][n]);
      }

      // LN over this wave's 32 token-rows x 64 head-cols; write transposed to LDS
      char* T = smem + 32768 + mat * 32768 + h * 8192;  // [64 d|e][64 s], 128B rows, swz
#pragma unroll
      for (int m = 0; m < 2; ++m) {
        float mu[4], rs[4];
#pragma unroll
        for (int r = 0; r < 4; ++r) {
          float s1 = 0.f, s2 = 0.f;
#pragma unroll
          for (int n = 0; n < 4; ++n) { float x = acc[m][n][r]; s1 += x; s2 += x * x; }
#pragma unroll
          for (int msk = 1; msk < 16; msk <<= 1) {
            s1 += __shfl_xor(s1, msk);
            s2 += __shfl_xor(s2, msk);
          }
          mu[r] = s1 * (1.f / 64.f);
          float var = s2 * (1.f / 64.f) - mu[r] * mu[r];
          rs[r] = rsqrtf(var + LN_EPS);
        }
#pragma unroll
        for (int n = 0; n < 4; ++n) {
          bf16x4 pk;
#pragma unroll
          for (int r = 0; r < 4; ++r)
            pk[r] = f2bf((acc[m][n][r] - mu[r]) * rs[r] * gv[n] + bv[n]);
          int d = n * 16 + l15;           // d&7 == l7
          int sb = mh * 64 + m * 32 + l4 * 8;   // byte of s0 = mh*32 + m*16 + l4*4
          *(bf16x4*)(T + d * 128 + (sb ^ (l7 << 4))) = pk;
        }
      }
    }

    __syncthreads();                      // kT + vT ready

    // outer product: wave = (head h, e-half eh=mh); ACCUMULATE into kvacc
    {
      const int eh = mh;
#pragma unroll
      for (int kk = 0; kk < 2; ++kk) {    // 64 tokens = 2 K-steps
        bf16x8 ak[4], b2[2];
#pragma unroll
        for (int fd = 0; fd < 4; ++fd) {
          int d = fd * 16 + l15;
          ak[fd] = *(const bf16x8*)(smem + 32768 + h * 8192 + d * 128 +
                                    ((kk * 64 + l4 * 16) ^ (l7 << 4)));
        }
#pragma unroll
        for (int c = 0; c < 2; ++c) {
          int e = (eh * 2 + c) * 16 + l15;
          b2[c] = *(const bf16x8*)(smem + 65536 + h * 8192 + e * 128 +
                                   ((kk * 64 + l4 * 16) ^ (l7 << 4)));
        }
#pragma unroll
        for (int fd = 0; fd < 4; ++fd)
#pragma unroll
          for (int c = 0; c < 2; ++c)
            kvacc[fd][c] = MFMA16(ak[fd], b2[c], kvacc[fd][c]);
      }
    }
    // next stage's post-stage __syncthreads orders stage(t+1)/LN(t+1) vs outer(t)
  }

  // store P in fragment order (flat layout as before): coalesced 512B
  unsigned short* Ph = P + ((size_t)((b * 64 + ptile2) * 4 + h) << 12);
#pragma unroll
  for (int fd = 0; fd < 4; ++fd)
#pragma unroll
    for (int c = 0; c < 2; ++c) {
      bf16x4 pk;
#pragma unroll
      for (int r = 0; r < 4; ++r) pk[r] = f2bf(kvacc[fd][c][r]);
      *(bf16x4*)(Ph + (fd * 4 + mh * 2 + c) * 256 + lane * 4) = pk;
    }
}

// ---------------- reduce: kvf = sum_p P (64 partials); blocks 0-15 build wqT ---------
__global__ __launch_bounds__(256)
void gka_red(const unsigned short* __restrict__ P, float* __restrict__ kvf,
             const float* __restrict__ wq, unsigned short* __restrict__ wqt) {
  __shared__ unsigned short T[64 * 66];
  int blk = blockIdx.x, tid = threadIdx.x;
  {
    int gtid = blk * 256 + tid;               // 131072 = 16384 quads x 8 chunks
    int chunk = gtid & 7;
    int qid = gtid >> 3;                      // (b<<12) | (h<<10) | t4
    int b = qid >> 12, h = (qid >> 10) & 3, t4 = qid & 1023;
    const unsigned short* p0 = P + ((size_t)(b * 256 + h) << 12) + t4 * 4;
    float s0 = 0.f, s1 = 0.f, s2 = 0.f, s3 = 0.f;
#pragma unroll
    for (int s = 0; s < 8; ++s) {             // 64 partials / 8 chunks
      int p = chunk * 8 + s;
      uint2 u = *(const uint2*)(p0 + ((size_t)p << 14));
      s0 += bf2f(u.x & 0xffffu); s1 += bf2f(u.x >> 16);
      s2 += bf2f(u.y & 0xffffu); s3 += bf2f(u.y >> 16);
    }
#pragma unroll
    for (int msk = 1; msk < 8; msk <<= 1) {
      s0 += __shfl_xor(s0, msk); s1 += __shfl_xor(s1, msk);
      s2 += __shfl_xor(s2, msk); s3 += __shfl_xor(s3, msk);
    }
    if (chunk == 0) {
      f32x4 r; r[0] = s0; r[1] = s1; r[2] = s2; r[3] = s3;
      *(f32x4*)(kvf + (qid << 2)) = r;
    }
  }

  if (blk < 16) {                         // 64x64 tile transpose wqt[i][j] = wq[j][i]
    int ti = blk >> 2, tj = blk & 3;
#pragma unroll
    for (int it = 0; it < 4; ++it) {
      int g = tid + it * 256;               // 1024 granules of 4 floats
      int jl = g >> 4, g4 = g & 15;
      f32x4 f = *(const f32x4*)(wq + (tj * 64 + jl) * 256 + ti * 64 + g4 * 4);
#pragma unroll
      for (int q = 0; q < 4; ++q) T[jl * 66 + g4 * 4 + q] = (unsigned short)f2bf(f[q]);
    }
    __syncthreads();
#pragma unroll
    for (int it = 0; it < 2; ++it) {
      int g = tid + it * 256;               // 512 output groups of 8
      int il = g >> 3, j8 = g & 7;
      bf16x8 v;
#pragma unroll
      for (int q = 0; q < 8; ++q) v[q] = (short)T[(j8 * 8 + q) * 66 + il];
      *(bf16x8*)(wqt + (ti * 64 + il) * 256 + tj * 64 + j8 * 8) = v;
    }
  }
}

// ---------------- pass B (merged m1+wc): per (b, o-half) block ----------------------
// phase 1: M1T[o_loc][j=h*64+d] = sum_e kv[b,h,d,e]/S * wo[o][h*64+e]  -> LDS (swz)
// phase 2: WcT frag-major: Wc[i][o] = sum_j wqT[i][j] * M1T[o_loc][j]
__global__ __launch_bounds__(512)
void gka_wc(const float* __restrict__ kvf, const float* __restrict__ wo,
            const unsigned short* __restrict__ wqt, unsigned short* __restrict__ wcf) {
  __shared__ char M1[65536];              // [128 o_loc][256 j] bf16, 512B rows, swz
  const int tid = threadIdx.x;
  const int lane = tid & 63;
  const int wid = tid >> 6;               // 8 waves
  const int l15 = lane & 15, l4 = lane >> 4;
  const int blk = blockIdx.x;             // 8 = 4b x 2 o-half
  const int b = blk >> 1, oh = blk & 1;
  const float invS = 1.f / (float)SEQ;

  // ---- phase 1: wave -> (wo_t = wid>>2 o-64-range, wj = wid&3 head) ----
  {
    const int wo_t = wid >> 2, wj = wid & 3;
    const float* kvh = kvf + ((b * 4 + wj) << 12);
    f32x4 acc[4][4];
#pragma unroll
    for (int m = 0; m < 4; ++m)
#pragma unroll
      for (int n = 0; n < 4; ++n) acc[m][n] = (f32x4)0.0f;

#pragma unroll
    for (int kk = 0; kk < 2; ++kk) {      // K = 64 (e)
      bf16x8 af[4], bw[4];
#pragma unroll
      for (int m = 0; m < 4; ++m) {
        // gather (d = m*16+l15, e = kk*32+l4*8+j) from kv fragment layout
        int base = (m * 4 + kk * 2 + (l4 >> 1)) * 256 +
                   ((l15 >> 2) * 16 + (l4 & 1) * 8) * 4 + (l15 & 3);
        bf16x8 v;
#pragma unroll
        for (int j = 0; j < 8; ++j) v[j] = f2bf(kvh[base + j * 4] * invS);
        af[m] = v;
      }
#pragma unroll
      for (int n = 0; n < 4; ++n) {
        int o = oh * 128 + wo_t * 64 + n * 16 + l15;
        const f32x4* wp = (const f32x4*)(wo + (size_t)o * 256 + wj * 64 + kk * 32 + l4 * 8);
        bw[n] = cvt8(wp[0], wp[1]);
      }
#pragma unroll
      for (int m = 0; m < 4; ++m)
#pragma unroll
        for (int n = 0; n < 4; ++n)
          acc[m][n] = MFMA16(af[m], bw[n], acc[m][n]);
    }
    // store to LDS M1T: row = o_loc, col j = wj*64 + m*16 + l4*4 + r (bf16x4), swz
#pragma unroll
    for (int m = 0; m < 4; ++m)
#pragma unroll
      for (int n = 0; n < 4; ++n) {
        int row = wo_t * 64 + n * 16 + l15;
        int jb = (wj * 64 + m * 16 + l4 * 4) * 2;
        bf16x4 pk;
#pragma unroll
        for (int r = 0; r < 4; ++r) pk[r] = f2bf(acc[m][n][r]);
        *(bf16x4*)(M1 + row * 512 + (jb ^ ((row & 7) << 4))) = pk;
      }
  }

  __syncthreads();

  // ---- phase 2: wave -> (wi = wid>>1 i-64-range, wo2 = wid&1 o-64-range) ----
  {
    const int wi = wid >> 1, wo2 = wid & 1;
    f32x4 acc[4][4];
#pragma unroll
    for (int m = 0; m < 4; ++m)
#pragma unroll
      for (int n = 0; n < 4; ++n) acc[m][n] = (f32x4)0.0f;

#pragma unroll
    for (int kk = 0; kk < 8; ++kk) {      // K = 256 (j)
      bf16x8 af[4], bw[4];
#pragma unroll
      for (int m = 0; m < 4; ++m) {
        int i = wi * 64 + m * 16 + l15;
        af[m] = *(const bf16x8*)(wqt + i * 256 + kk * 32 + l4 * 8);
      }
#pragma unroll
      for (int n = 0; n < 4; ++n) {
        int row = wo2 * 64 + n * 16 + l15;
        bw[n] = *(const bf16x8*)(M1 + row * 512 +
                                 ((kk * 64 + l4 * 16) ^ ((row & 7) << 4)));
      }
#pragma unroll
      for (int m = 0; m < 4; ++m)
#pragma unroll
        for (int n = 0; n < 4; ++n)
          acc[m][n] = MFMA16(af[m], bw[n], acc[m][n]);
    }
    // store to fragment-major wcf for gka_out
    const int o6 = oh * 2 + wo2;
#pragma unroll
    for (int m = 0; m < 4; ++m)
#pragma unroll
      for (int n = 0; n < 4; ++n) {
        int kko = wi * 2 + (m >> 1);
        int laneo = ((m & 1) * 2 + (l4 >> 1)) * 16 + l15;
        int jo = (l4 & 1) * 4;
        bf16x4 pk;
#pragma unroll
        for (int r = 0; r < 4; ++r) pk[r] = f2bf(acc[m][n][r]);
        *(bf16x4*)(wcf + ((size_t)b << 16) +
                   (((((o6 * 8 + kko) * 4 + n) * 64) + laneo) << 3) + jo) = pk;
      }
  }
}

// ---------------- pass C: out = seq @ Wc[b] + bo  (1024 x 32-token tiles, LDS) -------
__global__ __launch_bounds__(256, 4)
void gka_out(const float* __restrict__ seq, const unsigned short* __restrict__ wcf,
             const float* __restrict__ bo, float* __restrict__ out) {
  __shared__ char smem[16384];
  const int tid = threadIdx.x;
  const int lane = tid & 63;
  const int wid = tid >> 6;               // wave -> o-range (64 cols)
  const int l15 = lane & 15, l4 = lane >> 4, l7 = lane & 7;
  const int tile = blockIdx.x;            // 1024 = 4b x 256 tiles of 32 rows
  const int b = tile >> 8;
  const int srow = (tile & 255) * 32;

  stage_x32(smem, seq + (size_t)(b * SEQ + srow) * EMBED, tid);

  const unsigned short* Wf = wcf + ((size_t)b << 16);
  float bov[4];
#pragma unroll
  for (int n = 0; n < 4; ++n) bov[n] = bo[wid * 64 + n * 16 + l15];

  f32x4 acc[2][4];
#pragma unroll
  for (int m = 0; m < 2; ++m)
#pragma unroll
    for (int n = 0; n < 4; ++n) acc[m][n] = (f32x4)0.0f;

  __syncthreads();

#pragma unroll
  for (int kk = 0; kk < 8; ++kk) {        // K = 256, no barriers
    bf16x8 af[2], bw[4];
#pragma unroll
    for (int m = 0; m < 2; ++m) {
      int row = m * 16 + l15;
      af[m] = *(const bf16x8*)(smem + row * 512 + ((kk * 64 + l4 * 16) ^ (l7 << 4)));
    }
#pragma unroll
    for (int n = 0; n < 4; ++n)           // coalesced 512B per wave, L2-resident
      bw[n] = *(const bf16x8*)(Wf + ((((wid * 8 + kk) * 4 + n) * 64 + lane) << 3));
#pragma unroll
    for (int m = 0; m < 2; ++m)
#pragma unroll
      for (int n = 0; n < 4; ++n)
        acc[m][n] = MFMA16(af[m], bw[n], acc[m][n]);
  }

  float* dst = out + (size_t)(b * SEQ + srow) * EMBED;
#pragma unroll
  for (int m = 0; m < 2; ++m)
#pragma unroll
    for (int n = 0; n < 4; ++n)
#pragma unroll
      for (int r = 0; r < 4; ++r)
        dst[(size_t)(m * 16 + l4 * 4 + r) * EMBED + wid * 64 + n * 16 + l15] =
            acc[m][n][r] + bov[n];
}

extern "C" void kernel_launch(void* const* d_in, const int* in_sizes, int n_in,
                              void* d_out, int out_size, void* d_ws, size_t ws_size,
                              hipStream_t stream) {
  const float* seq = (const float*)d_in[0];
  const float* wq  = (const float*)d_in[1];
  const float* wk  = (const float*)d_in[2];
  const float* wv  = (const float*)d_in[3];
  const float* wo  = (const float*)d_in[4];
  const float* bo  = (const float*)d_in[5];
  const float* lkg = (const float*)d_in[6];
  const float* lkb = (const float*)d_in[7];
  const float* lvg = (const float*)d_in[8];
  const float* lvb = (const float*)d_in[9];
  float* out = (float*)d_out;
  char* ws = (char*)d_ws;

  unsigned short* wkf = (unsigned short*)(ws + 0);
  unsigned short* wvf = (unsigned short*)(ws + 131072);
  unsigned short* wqt = (unsigned short*)(ws + 262144);
  float*          kvf = (float*)(ws + 524288);
  unsigned short* wcf = (unsigned short*)(ws + 1310720);
  unsigned short* P   = (unsigned short*)d_out;   // 8.4MB partials, overwritten by gka_out

  gka_prep<<<64, 256, 0, stream>>>(wk, wv, wkf, wvf);
  gka_kv<<<256, 512, 0, stream>>>(seq, wkf, wvf, lkg, lkb, lvg, lvb, P);
  gka_red<<<512, 256, 0, stream>>>(P, kvf, wq, wqt);
  gka_wc<<<8, 512, 0, stream>>>(kvf, wo, wqt, wcf);
  gka_out<<<1024, 256, 0, stream>>>(seq, wcf, bo, out);
}